// Round 7
// baseline (204.381 us; speedup 1.0000x reference)
//
#include <hip/hip_runtime.h>
#include <math.h>

#define NEG_SLOPE 0.2f

typedef float f32x4 __attribute__((ext_vector_type(4)));
typedef short bf16x8 __attribute__((ext_vector_type(8)));
typedef unsigned short ushortv8 __attribute__((ext_vector_type(8)));

__device__ __forceinline__ unsigned short f2bf(float f) {
    union { float f; unsigned u; } uu; uu.f = f;
    unsigned r = uu.u + 0x7FFF + ((uu.u >> 16) & 1);   // RNE, no NaN inputs
    return (unsigned short)(r >> 16);
}
__device__ __forceinline__ float bf2f(unsigned short u) {
    union { unsigned u; float f; } x; x.u = ((unsigned)u) << 16; return x.f;
}

// ---------------------------------------------------------------------------
// prep: x->bf16 convert | W1 transpose | W2 transpose | zero counts+cursor.
// (histogram moved to its own kernel so zeroing can live here)
// ---------------------------------------------------------------------------
__global__ void prep_kernel(const float* __restrict__ x, unsigned short* __restrict__ xb,
                            const float* __restrict__ W1, unsigned short* __restrict__ Wt1,
                            const float* __restrict__ W2, unsigned short* __restrict__ Wt2,
                            int* __restrict__ counts, int* __restrict__ cursor,
                            int n4x, int N)
{
    int t = blockIdx.x * 256 + threadIdx.x;
    if (t < n4x) {
        float4 v = ((const float4*)x)[t];
        ushort4 o;
        o.x = f2bf(v.x); o.y = f2bf(v.y); o.z = f2bf(v.z); o.w = f2bf(v.w);
        ((ushort4*)xb)[t] = o;
        return;
    }
    int u = t - n4x;
    if (u < 32768) {                       // Wt1[256][128]
        int nn = u >> 7, k = u & 127;
        Wt1[u] = f2bf(W1[(size_t)k * 256 + nn]);
        return;
    }
    u -= 32768;
    if (u < 65536) {                       // Wt2[256][256]
        int nn = u >> 8, k = u & 255;
        Wt2[u] = f2bf(W2[(size_t)k * 256 + nn]);
        return;
    }
    u -= 65536;
    if (u < N) { counts[u] = 0; cursor[u] = 0; }
}

__global__ void hist_kernel(const int* __restrict__ dst, int* __restrict__ counts, int E)
{
    int e = blockIdx.x * 256 + threadIdx.x;
    if (e < E) atomicAdd(&counts[dst[e]], 1);
}

// ---------------------------------------------------------------------------
// MFMA GEMM (verbatim from round-6 passing kernel)
// ---------------------------------------------------------------------------
__global__ __launch_bounds__(256) void gemm_mfma(
    const unsigned short* __restrict__ A,
    const unsigned short* __restrict__ Bt,
    unsigned short* __restrict__ C,
    int M, int K)
{
    __shared__ unsigned short As[128 * 64];
    __shared__ unsigned short Bs[128 * 64];
    const int tid  = threadIdx.x;
    const int lane = tid & 63;
    const int wave = tid >> 6;
    const int wr = wave >> 1, wc = wave & 1;
    const int row0 = blockIdx.x * 128;
    const int col0 = blockIdx.y * 128;

    f32x4 acc[4][4] = {};

    for (int k0 = 0; k0 < K; k0 += 64) {
        ushortv8 va[4], vb[4];
        #pragma unroll
        for (int i = 0; i < 4; ++i) {
            int c  = i * 256 + tid;
            int r  = c >> 3, cc = c & 7;
            int ga = row0 + r; if (ga >= M) ga = M - 1;
            va[i] = *(const ushortv8*)(A  + (size_t)ga * K + k0 + cc * 8);
            vb[i] = *(const ushortv8*)(Bt + (size_t)(col0 + r) * K + k0 + cc * 8);
        }
        __syncthreads();
        #pragma unroll
        for (int i = 0; i < 4; ++i) {
            int c  = i * 256 + tid;
            int r  = c >> 3, cc = c & 7;
            int sl = cc ^ (r & 7);
            *(ushortv8*)(As + r * 64 + sl * 8) = va[i];
            *(ushortv8*)(Bs + r * 64 + sl * 8) = vb[i];
        }
        __syncthreads();

        #pragma unroll
        for (int kk = 0; kk < 2; ++kk) {
            const int kbyte = kk * 64 + ((lane >> 4) << 4);
            bf16x8 af[4], bfr[4];
            #pragma unroll
            for (int m = 0; m < 4; ++m) {
                int r = wr * 64 + m * 16 + (lane & 15);
                af[m] = *(const bf16x8*)((const char*)As + r * 128 + (kbyte ^ ((r & 7) << 4)));
            }
            #pragma unroll
            for (int n = 0; n < 4; ++n) {
                int r = wc * 64 + n * 16 + (lane & 15);
                bfr[n] = *(const bf16x8*)((const char*)Bs + r * 128 + (kbyte ^ ((r & 7) << 4)));
            }
            #pragma unroll
            for (int m = 0; m < 4; ++m)
                #pragma unroll
                for (int n = 0; n < 4; ++n)
                    acc[m][n] = __builtin_amdgcn_mfma_f32_16x16x32_bf16(
                        af[m], bfr[n], acc[m][n], 0, 0, 0);
        }
        __syncthreads();
    }

    #pragma unroll
    for (int m = 0; m < 4; ++m) {
        int rbase = row0 + wr * 64 + m * 16 + ((lane >> 4) << 2);
        #pragma unroll
        for (int j = 0; j < 4; ++j) {
            int grow = rbase + j;
            if (grow < M) {
                #pragma unroll
                for (int n = 0; n < 4; ++n)
                    C[(size_t)grow * 256 + col0 + wc * 64 + n * 16 + (lane & 15)] =
                        f2bf(acc[m][n][j]);
            }
        }
    }
}

// ---------------------------------------------------------------------------
// Attention logits from bf16 h. (verbatim from round-6 passing kernel)
// ---------------------------------------------------------------------------
__global__ void att_kernel(const unsigned short* __restrict__ h,
                           const float* __restrict__ att_s,
                           const float* __restrict__ att_d,
                           float* __restrict__ a_s, float* __restrict__ a_d, int N)
{
    int t = blockIdx.x * 256 + threadIdx.x;
    if (t >= N * 8) return;
    int n = t >> 3, hh = t & 7;
    const ushortv8* hp = (const ushortv8*)(h + (size_t)n * 256 + hh * 32);
    const float*    ap = att_s + hh * 32;
    const float*    bp = att_d + hh * 32;
    float ss = 0.f, dd = 0.f;
    #pragma unroll
    for (int i = 0; i < 4; ++i) {
        ushortv8 hv = hp[i];
        #pragma unroll
        for (int q = 0; q < 8; ++q) {
            float f = bf2f(hv[q]);
            ss += f * ap[i*8 + q];
            dd += f * bp[i*8 + q];
        }
    }
    a_s[t] = ss; a_d[t] = dd;
}

// ---------------------------------------------------------------------------
// CSR scan kernels (verbatim from round-6 passing kernel)
// ---------------------------------------------------------------------------
__global__ __launch_bounds__(256) void scan_blk(
    const int* __restrict__ counts, int* __restrict__ incl, int* __restrict__ bsum, int N)
{
    __shared__ int wtot[4], wexc[4];
    int t = blockIdx.x * 256 + threadIdx.x;
    int lane = threadIdx.x & 63, wid = threadIdx.x >> 6;
    int v = (t < N) ? counts[t] : 0;
    int s = v;
    #pragma unroll
    for (int off = 1; off < 64; off <<= 1) {
        int u = __shfl_up(s, off);
        if (lane >= off) s += u;
    }
    if (lane == 63) wtot[wid] = s;
    __syncthreads();
    if (threadIdx.x == 0) {
        int r = 0;
        #pragma unroll
        for (int w = 0; w < 4; ++w) { wexc[w] = r; r += wtot[w]; }
    }
    __syncthreads();
    int out = s + wexc[wid];
    if (t < N) incl[t] = out;
    if (threadIdx.x == 255) bsum[blockIdx.x] = out;
}

__global__ __launch_bounds__(256) void scan_top(int* __restrict__ bsum, int nb)
{
    __shared__ int wtot[4], wexc[4];
    int tid = threadIdx.x;
    int lane = tid & 63, wid = tid >> 6;
    int v = (tid < nb) ? bsum[tid] : 0;
    int s = v;
    #pragma unroll
    for (int off = 1; off < 64; off <<= 1) {
        int u = __shfl_up(s, off);
        if (lane >= off) s += u;
    }
    if (lane == 63) wtot[wid] = s;
    __syncthreads();
    if (tid == 0) {
        int r = 0;
        #pragma unroll
        for (int w = 0; w < 4; ++w) { wexc[w] = r; r += wtot[w]; }
    }
    __syncthreads();
    if (tid < nb) bsum[tid] = s + wexc[wid] - v;
}

__global__ void fill_kernel(const int* __restrict__ src, const int* __restrict__ dst,
                            const int* __restrict__ incl, const int* __restrict__ bsum,
                            int* __restrict__ rowptr, int* __restrict__ cursor,
                            int* __restrict__ esrc, int N, int E)
{
    int t = blockIdx.x * 256 + threadIdx.x;
    if (t < N) {
        rowptr[t + 1] = incl[t] + bsum[t >> 8];
        if (t == 0) rowptr[0] = 0;
    }
    if (t < E) {
        int d = dst[t];
        int rp = bsum[d >> 8] + ((d & 255) ? incl[d - 1] : 0);
        int pos = rp + atomicAdd(&cursor[d], 1);
        esrc[pos] = src[t];
    }
}

// ---------------------------------------------------------------------------
// Per-node GAT aggregation. One wave per node (4/block). half=lane>>5 handles
// every other edge; sl=lane&31 owns channels sl*8..sl*8+7; head=sl>>2.
// This round: 8-edge block hoists esrc, a_s AND h loads ahead of the exp/fma
// chains (12 independent loads in flight).
// ---------------------------------------------------------------------------
template<int LAYER>
__global__ __launch_bounds__(256) void gat_agg(
    const unsigned short* __restrict__ h, const float* __restrict__ a_s,
    const float* __restrict__ a_d, const int* __restrict__ rowptr,
    const int* __restrict__ esrc, const float* __restrict__ bias,
    float* __restrict__ out, unsigned short* __restrict__ out_b, int N)
{
    int n = blockIdx.x * 4 + (threadIdx.x >> 6);
    if (n >= N) return;
    const int lane = threadIdx.x & 63;
    const int half = lane >> 5;
    const int sl   = lane & 31;
    const int head = sl >> 2;
    int beg = rowptr[n];
    int deg = rowptr[n + 1] - beg;

    if (deg == 0) {
        if (LAYER == 1) {
            if (half == 0) {
                ushortv8 o;
                #pragma unroll
                for (int q = 0; q < 8; ++q) {
                    float b = bias[sl*8 + q];
                    o[q] = f2bf(b > 0.f ? b : expf(b) - 1.f);
                }
                *(ushortv8*)(out_b + (size_t)n*256 + sl*8) = o;
            }
        } else {
            if (lane < 4) {
                #pragma unroll
                for (int q = 0; q < 8; ++q)
                    out[(size_t)n*32 + lane*8 + q] = bias[lane*8 + q];
            }
        }
        return;
    }

    float adn = a_d[(size_t)n*8 + head];
    float dsum = 0.f;
    float acc[8] = {0.f,0.f,0.f,0.f,0.f,0.f,0.f,0.f};

    int j0 = 0;
    for (; j0 + 8 <= deg; j0 += 8) {
        int sv[4];
        #pragma unroll
        for (int k = 0; k < 4; ++k) sv[k] = esrc[beg + j0 + 2*k + half];
        float av[4];
        #pragma unroll
        for (int k = 0; k < 4; ++k) av[k] = a_s[(size_t)sv[k]*8 + head];
        ushortv8 hv[4];
        #pragma unroll
        for (int k = 0; k < 4; ++k)
            hv[k] = *(const ushortv8*)(h + (size_t)sv[k]*256 + sl*8);
        #pragma unroll
        for (int k = 0; k < 4; ++k) {
            float e = av[k] + adn;
            e = (e > 0.f) ? e : NEG_SLOPE * e;
            float p = __expf(e);
            dsum += p;
            #pragma unroll
            for (int q = 0; q < 8; ++q) acc[q] += p * bf2f(hv[k][q]);
        }
    }
    for (; j0 + 2 <= deg; j0 += 2) {
        int s = esrc[beg + j0 + half];
        float e = a_s[(size_t)s*8 + head] + adn;
        e = (e > 0.f) ? e : NEG_SLOPE * e;
        float p = __expf(e);
        dsum += p;
        ushortv8 hv = *(const ushortv8*)(h + (size_t)s*256 + sl*8);
        #pragma unroll
        for (int q = 0; q < 8; ++q) acc[q] += p * bf2f(hv[q]);
    }
    if (j0 < deg) {                      // single leftover edge (half 0 only)
        int s = esrc[beg + j0];
        if (half == 0) {
            float e = a_s[(size_t)s*8 + head] + adn;
            e = (e > 0.f) ? e : NEG_SLOPE * e;
            float p = __expf(e);
            dsum += p;
            ushortv8 hv = *(const ushortv8*)(h + (size_t)s*256 + sl*8);
            #pragma unroll
            for (int q = 0; q < 8; ++q) acc[q] += p * bf2f(hv[q]);
        }
    }

    // combine the two halves
    dsum += __shfl_xor(dsum, 32);
    #pragma unroll
    for (int q = 0; q < 8; ++q) acc[q] += __shfl_xor(acc[q], 32);
    float invd = 1.f / (dsum + 1e-16f);

    if (LAYER == 1) {
        if (half == 0) {
            ushortv8 o;
            #pragma unroll
            for (int q = 0; q < 8; ++q) {
                float val = acc[q] * invd + bias[sl*8 + q];
                o[q] = f2bf(val > 0.f ? val : expf(val) - 1.f);
            }
            *(ushortv8*)(out_b + (size_t)n*256 + sl*8) = o;
        }
    } else {
        #pragma unroll
        for (int q = 0; q < 8; ++q) acc[q] *= invd;
        // mean across heads: heads live on lane bits 2..4
        #pragma unroll
        for (int m = 4; m <= 16; m <<= 1)
            #pragma unroll
            for (int q = 0; q < 8; ++q) acc[q] += __shfl_xor(acc[q], m);
        if (lane < 4) {
            float4 lo = make_float4(acc[0]*0.125f + bias[lane*8+0],
                                    acc[1]*0.125f + bias[lane*8+1],
                                    acc[2]*0.125f + bias[lane*8+2],
                                    acc[3]*0.125f + bias[lane*8+3]);
            float4 hi = make_float4(acc[4]*0.125f + bias[lane*8+4],
                                    acc[5]*0.125f + bias[lane*8+5],
                                    acc[6]*0.125f + bias[lane*8+6],
                                    acc[7]*0.125f + bias[lane*8+7]);
            *(float4*)(out + (size_t)n*32 + lane*8)     = lo;
            *(float4*)(out + (size_t)n*32 + lane*8 + 4) = hi;
        }
    }
}

// ---------------------------------------------------------------------------
extern "C" void kernel_launch(void* const* d_in, const int* in_sizes, int n_in,
                              void* d_out, int out_size, void* d_ws, size_t ws_size,
                              hipStream_t stream)
{
    const float* x   = (const float*)d_in[0];
    const int*   ei  = (const int*)  d_in[1];
    const float* W1  = (const float*)d_in[2];
    const float* as1 = (const float*)d_in[3];
    const float* ad1 = (const float*)d_in[4];
    const float* b1  = (const float*)d_in[5];
    const float* W2  = (const float*)d_in[6];
    const float* as2 = (const float*)d_in[7];
    const float* ad2 = (const float*)d_in[8];
    const float* b2  = (const float*)d_in[9];

    const int N = in_sizes[0] / 128;
    const int E = in_sizes[1] / 2;
    const int* srcp = ei;
    const int* dstp = ei + E;

    // ---- workspace layout ----
    char* ws = (char*)d_ws;
    unsigned short* hb    = (unsigned short*)ws;  ws += (size_t)N * 256 * 2;
    unsigned short* xb    = (unsigned short*)ws;  ws += (size_t)N * 128 * 2;
    unsigned short* out1b = (unsigned short*)ws;  ws += (size_t)N * 256 * 2;
    unsigned short* Wt1   = (unsigned short*)ws;  ws += 256 * 128 * 2;
    unsigned short* Wt2   = (unsigned short*)ws;  ws += 256 * 256 * 2;
    float*          a_s   = (float*)ws;           ws += (size_t)N * 8 * 4;
    float*          a_d   = (float*)ws;           ws += (size_t)N * 8 * 4;
    int*            counts= (int*)ws;             ws += (size_t)N * 4;
    int*            cursor= (int*)ws;             ws += (size_t)N * 4;
    int*            incl  = (int*)ws;             ws += (size_t)N * 4;
    int*            bsum  = (int*)ws;             ws += 256 * 4;
    int*            rowptr= (int*)ws;             ws += (size_t)(N + 1) * 4;
    int*            esrc  = (int*)ws;

    const int nb  = (N + 255) / 256;
    const int n4x = N * 32;                          // N*128/4

    // prep: cvt + W transposes + zero counts/cursor (no hipMemsetAsync)
    {
        int tot = n4x + 32768 + 65536 + N;
        prep_kernel<<<(tot + 255) / 256, 256, 0, stream>>>(
            x, xb, W1, Wt1, W2, Wt2, counts, cursor, n4x, N);
    }
    hist_kernel<<<(E + 255) / 256, 256, 0, stream>>>(dstp, counts, E);
    scan_blk<<<nb, 256, 0, stream>>>(counts, incl, bsum, N);
    scan_top<<<1, 256, 0, stream>>>(bsum, nb);
    fill_kernel<<<(E + 255) / 256, 256, 0, stream>>>(srcp, dstp, incl, bsum,
                                                     rowptr, cursor, esrc, N, E);

    const int gridM = (N + 127) / 128;

    // ---- layer 1 ----
    gemm_mfma<<<dim3(gridM, 2), 256, 0, stream>>>(xb, Wt1, hb, N, 128);
    att_kernel<<<(N * 8 + 255) / 256, 256, 0, stream>>>(hb, as1, ad1, a_s, a_d, N);
    gat_agg<1><<<(N + 3) / 4, 256, 0, stream>>>(hb, a_s, a_d, rowptr, esrc, b1,
                                                nullptr, out1b, N);

    // ---- layer 2 ----
    gemm_mfma<<<dim3(gridM, 2), 256, 0, stream>>>(out1b, Wt2, hb, N, 256);
    att_kernel<<<(N * 8 + 255) / 256, 256, 0, stream>>>(hb, as2, ad2, a_s, a_d, N);
    gat_agg<2><<<(N + 3) / 4, 256, 0, stream>>>(hb, a_s, a_d, rowptr, esrc, b2,
                                                (float*)d_out, nullptr, N);
}